// Round 3
// baseline (637.551 us; speedup 1.0000x reference)
//
#include <hip/hip_runtime.h>

#define F_IN  256
#define F_OUT 32
#define NPB   64        // nodes per bucket
#define NBMAX 1600      // max buckets (N <= 102400)

// ---------- init: zero cnt + gcnt, detect edge-index dtype ----------
// int64 little-endian with values < 2^31 => every odd 32-bit word is zero.
__global__ void k_init(int* __restrict__ cnt, int* __restrict__ gcnt,
                       const int* __restrict__ ei, int* __restrict__ flag,
                       int N, int NB) {
    int i = blockIdx.x * 256 + threadIdx.x;
    if (i < N) cnt[i] = 0;
    if (blockIdx.x == 0) {
        for (int b = threadIdx.x; b < NB; b += 256) gcnt[b] = 0;
        if (threadIdx.x == 0) {
            int o = 0;
            for (int k = 1; k < 64; k += 2) o |= ei[k];
            *flag = (o == 0) ? 1 : 0;
        }
    }
}

__device__ __forceinline__ int load_idx(const int* __restrict__ ei, int i, int mode64) {
    return mode64 ? ei[2 * i] : ei[i];
}

// ---------- A0: per-node degree + per-bucket counts ----------
__global__ __launch_bounds__(256) void k_count(const int* __restrict__ ei,
                                               int* __restrict__ cnt,
                                               int* __restrict__ gcnt,
                                               const int* __restrict__ flag,
                                               int E, int N, int NB) {
    __shared__ int hist[NBMAX];
    for (int b = threadIdx.x; b < NB; b += 256) hist[b] = 0;
    __syncthreads();
    int m64 = *flag;
    int base = blockIdx.x * (256 * 32);
    #pragma unroll 4
    for (int k = 0; k < 32; ++k) {
        int e = base + k * 256 + threadIdx.x;
        if (e < E) {
            int d = load_idx(ei, E + e, m64);
            if ((unsigned)d < (unsigned)N) {
                atomicAdd(&cnt[d], 1);
                atomicAdd(&hist[d >> 6], 1);
            }
        }
    }
    __syncthreads();
    for (int b = threadIdx.x; b < NB; b += 256) {
        int h = hist[b];
        if (h) atomicAdd(&gcnt[b], h);
    }
}

// ---------- scan: exclusive offsets over buckets ----------
__global__ __launch_bounds__(256) void k_scan(const int* __restrict__ gcnt,
                                              int* __restrict__ gbase,
                                              int* __restrict__ gcur, int NB, int E) {
    __shared__ int part[256];
    int t = threadIdx.x;
    int chunk = (NB + 255) / 256;
    int i0 = t * chunk;
    int sum = 0;
    for (int j = 0; j < chunk; ++j) {
        int i = i0 + j;
        if (i < NB) sum += gcnt[i];
    }
    part[t] = sum;
    __syncthreads();
    for (int off = 1; off < 256; off <<= 1) {
        int add = (t >= off) ? part[t - off] : 0;
        __syncthreads();
        part[t] += add;
        __syncthreads();
    }
    int run = part[t] - sum;  // exclusive prefix of this thread's chunk
    for (int j = 0; j < chunk; ++j) {
        int i = i0 + j;
        if (i < NB) {
            gbase[i] = run;
            gcur[i]  = run;
            run += gcnt[i];
        }
    }
    if (t == 0) gbase[NB] = E;
}

// ---------- A2: fill csr with packed (src<<6 | local_dst), bucketed ----------
// 16384 edges/block: per-block LDS histogram -> one global-atomic reservation
// per (block,bucket) -> ~10 consecutive entries per bucket per block, so
// scattered writes land in ~40-170B runs instead of isolated 4B stores.
__global__ __launch_bounds__(256) void k_fill2(const int* __restrict__ ei,
                                               int* __restrict__ gcur,
                                               int* __restrict__ csr,
                                               const int* __restrict__ flag,
                                               int E, int N, int NB) {
    __shared__ int hist[NBMAX];
    __shared__ int base[NBMAX];
    __shared__ int lcur[NBMAX];
    for (int b = threadIdx.x; b < NB; b += 256) { hist[b] = 0; lcur[b] = 0; }
    __syncthreads();
    int m64 = *flag;
    int e0 = blockIdx.x * (256 * 64);
    // phase 1: local histogram
    #pragma unroll 4
    for (int k = 0; k < 64; ++k) {
        int e = e0 + k * 256 + threadIdx.x;
        if (e < E) {
            int d = load_idx(ei, E + e, m64);
            if ((unsigned)d < (unsigned)N) atomicAdd(&hist[d >> 6], 1);
        }
    }
    __syncthreads();
    // phase 2: reserve contiguous ranges
    for (int b = threadIdx.x; b < NB; b += 256) {
        int h = hist[b];
        base[b] = h ? atomicAdd(&gcur[b], h) : 0;
    }
    __syncthreads();
    // phase 3: write packed entries
    #pragma unroll 4
    for (int k = 0; k < 64; ++k) {
        int e = e0 + k * 256 + threadIdx.x;
        if (e < E) {
            int d = load_idx(ei, E + e, m64);
            int s = load_idx(ei, e, m64);
            if ((unsigned)d < (unsigned)N && (unsigned)s < (unsigned)N) {
                int bkt = d >> 6;
                int pos = base[bkt] + atomicAdd(&lcur[bkt], 1);
                csr[pos] = (s << 6) | (d & 63);
            }
        }
    }
}

// ---------- register-tiled GEMM: hs[n][f] = (x@W)[n][f] * rsqrt(deg[n]) ----------
#define KC 64
#define LDP 68
__global__ __launch_bounds__(256) void k_gemm(const float* __restrict__ x,
                                              const float* __restrict__ W,
                                              const int* __restrict__ cnt,
                                              float* __restrict__ hs, int N) {
    __shared__ __align__(16) float sx[128 * LDP];
    __shared__ __align__(16) float sWt[F_OUT * LDP];
    const int tid = threadIdx.x;
    const int fbase = tid & 7;
    const int rbase = tid >> 3;
    const int row0 = blockIdx.x * 128;

    float acc[4][4];
    #pragma unroll
    for (int j = 0; j < 4; ++j)
        #pragma unroll
        for (int m = 0; m < 4; ++m) acc[j][m] = 0.f;

    for (int c = 0; c < F_IN / KC; ++c) {
        #pragma unroll
        for (int i = 0; i < 8; ++i) {
            int flat4 = i * 256 + tid;
            int r = flat4 >> 4;
            int q = flat4 & 15;
            float4 v = make_float4(0.f, 0.f, 0.f, 0.f);
            if (row0 + r < N)
                v = ((const float4*)x)[(size_t)(row0 + r) * (F_IN / 4) + c * (KC / 4) + q];
            *(float4*)(sx + r * LDP + q * 4) = v;
        }
        #pragma unroll
        for (int i = 0; i < 8; ++i) {
            int flat = i * 256 + tid;
            int k = flat >> 5;
            int f = flat & 31;
            sWt[f * LDP + k] = W[(size_t)(c * KC + k) * F_OUT + f];
        }
        __syncthreads();

        #pragma unroll 4
        for (int k0 = 0; k0 < KC; k0 += 4) {
            float4 wv[4], xv[4];
            #pragma unroll
            for (int m = 0; m < 4; ++m)
                wv[m] = *(const float4*)(sWt + (fbase + 8 * m) * LDP + k0);
            #pragma unroll
            for (int j = 0; j < 4; ++j)
                xv[j] = *(const float4*)(sx + (rbase + 32 * j) * LDP + k0);
            #pragma unroll
            for (int j = 0; j < 4; ++j)
                #pragma unroll
                for (int m = 0; m < 4; ++m)
                    acc[j][m] += xv[j].x * wv[m].x + xv[j].y * wv[m].y +
                                 xv[j].z * wv[m].z + xv[j].w * wv[m].w;
        }
        __syncthreads();
    }

    #pragma unroll
    for (int j = 0; j < 4; ++j) {
        int row = row0 + rbase + 32 * j;
        if (row < N) {
            float di = rsqrtf((float)cnt[row] + 1.0f);
            #pragma unroll
            for (int m = 0; m < 4; ++m)
                hs[(size_t)row * F_OUT + fbase + 8 * m] = acc[j][m] * di;
        }
    }
}

// ---------- Pass B: per-bucket LDS accumulate + single coalesced out write ----------
__global__ __launch_bounds__(256) void k_passB(const int* __restrict__ csr,
                                               const int* __restrict__ gbase,
                                               const int* __restrict__ cnt,
                                               const float* __restrict__ hs,
                                               const float* __restrict__ b,
                                               float* __restrict__ out, int N) {
    __shared__ float acc[NPB * F_OUT];  // 8 KB
    const int tid = threadIdx.x;
    const int bkt = blockIdx.x;
    for (int i = tid; i < NPB * F_OUT; i += 256) acc[i] = 0.f;
    __syncthreads();

    const int s = gbase[bkt];
    const int e = gbase[bkt + 1];
    const int f = tid & 31;
    const int g = tid >> 5;  // 8 half-wave groups, one entry each

    int i = s + g;
    for (; i + 24 < e; i += 32) {
        int p0 = csr[i], p1 = csr[i + 8], p2 = csr[i + 16], p3 = csr[i + 24];
        float v0 = hs[(size_t)(p0 >> 6) * F_OUT + f];
        float v1 = hs[(size_t)(p1 >> 6) * F_OUT + f];
        float v2 = hs[(size_t)(p2 >> 6) * F_OUT + f];
        float v3 = hs[(size_t)(p3 >> 6) * F_OUT + f];
        atomicAdd(&acc[(p0 & 63) * F_OUT + f], v0);
        atomicAdd(&acc[(p1 & 63) * F_OUT + f], v1);
        atomicAdd(&acc[(p2 & 63) * F_OUT + f], v2);
        atomicAdd(&acc[(p3 & 63) * F_OUT + f], v3);
    }
    for (; i < e; i += 8) {
        int p = csr[i];
        atomicAdd(&acc[(p & 63) * F_OUT + f], hs[(size_t)(p >> 6) * F_OUT + f]);
    }
    __syncthreads();

    const int n0 = bkt * NPB;
    for (int idx = tid; idx < NPB * F_OUT; idx += 256) {
        int n = n0 + (idx >> 5);
        if (n < N) {
            int ff = idx & 31;
            float di = rsqrtf((float)cnt[n] + 1.0f);
            out[(size_t)n * F_OUT + ff] =
                b[ff] + di * (hs[(size_t)n * F_OUT + ff] + acc[idx]);
        }
    }
}

extern "C" void kernel_launch(void* const* d_in, const int* in_sizes, int n_in,
                              void* d_out, int out_size, void* d_ws, size_t ws_size,
                              hipStream_t stream) {
    const float* x  = (const float*)d_in[0];
    const int*   ei = (const int*)d_in[1];
    const float* W  = (const float*)d_in[2];
    const float* b  = (const float*)d_in[3];
    float* out = (float*)d_out;

    const int N = in_sizes[0] / F_IN;   // 100000
    const int E = in_sizes[1] / 2;      // 1600000
    const int NB = (N + NPB - 1) / NPB; // 1563

    // workspace layout (~19.6 MB)
    float* hs    = (float*)d_ws;                     // N*32 floats
    int*   cnt   = (int*)(hs + (size_t)N * F_OUT);   // N
    int*   gcnt  = cnt + N;                          // NB
    int*   gbase = gcnt + NB;                        // NB+1
    int*   gcur  = gbase + NB + 1;                   // NB
    int*   flag  = gcur + NB;                        // 1
    int*   csr   = flag + 1;                         // E

    k_init <<<(N + 255) / 256, 256, 0, stream>>>(cnt, gcnt, ei, flag, N, NB);
    k_count<<<(E + 256 * 32 - 1) / (256 * 32), 256, 0, stream>>>(ei, cnt, gcnt, flag, E, N, NB);
    k_scan <<<1, 256, 0, stream>>>(gcnt, gbase, gcur, NB, E);
    k_fill2<<<(E + 256 * 64 - 1) / (256 * 64), 256, 0, stream>>>(ei, gcur, csr, flag, E, N, NB);
    k_gemm <<<(N + 127) / 128, 256, 0, stream>>>(x, W, cnt, hs, N);
    k_passB<<<NB, 256, 0, stream>>>(csr, gbase, cnt, hs, b, out, N);
}

// Round 5
// 442.325 us; speedup vs baseline: 1.4414x; 1.4414x over previous
//
#include <hip/hip_runtime.h>

#define F_IN  256
#define F_OUT 32

// ---------- init: zero cnt, detect edge-index dtype ----------
// int64 little-endian with values < 2^31 => every odd 32-bit word is zero.
__global__ void k_init(int* __restrict__ cnt, const int* __restrict__ ei,
                       int* __restrict__ flag, int N) {
    int i = blockIdx.x * 256 + threadIdx.x;
    if (i < N) cnt[i] = 0;
    if (blockIdx.x == 0 && threadIdx.x == 0) {
        int o = 0;
        for (int k = 1; k < 64; k += 2) o |= ei[k];
        *flag = (o == 0) ? 1 : 0;
    }
}

__device__ __forceinline__ int load_idx(const int* __restrict__ ei, int i, int mode64) {
    return mode64 ? ei[2 * i] : ei[i];
}

// ---------- degree count: 4 edges/thread, vectorized dst reads ----------
__global__ __launch_bounds__(256) void k_count(const int* __restrict__ ei,
                                               int* __restrict__ cnt,
                                               const int* __restrict__ flag,
                                               int E, int N) {
    int m64 = *flag;
    int t = blockIdx.x * 256 + threadIdx.x;
    int e0 = t * 4;
    if (e0 >= E) return;
    int d[4];
    if (e0 + 3 < E) {
        if (m64) {
            const int4* base = (const int4*)(ei + 2 * (size_t)E);
            int4 a = base[2 * t];
            int4 c = base[2 * t + 1];
            d[0] = a.x; d[1] = a.z; d[2] = c.x; d[3] = c.z;
        } else {
            int4 a = *(const int4*)(ei + (size_t)E + e0);
            d[0] = a.x; d[1] = a.y; d[2] = a.z; d[3] = a.w;
        }
        #pragma unroll
        for (int j = 0; j < 4; ++j)
            if ((unsigned)d[j] < (unsigned)N) atomicAdd(&cnt[d[j]], 1);
    } else {
        for (int e = e0; e < E; ++e) {
            int dd = load_idx(ei, E + e, m64);
            if ((unsigned)dd < (unsigned)N) atomicAdd(&cnt[dd], 1);
        }
    }
}

// ---------- register-tiled GEMM ----------
// hs[n][f] = (x@W)[n][f] * dinv[n];  out[n][f] = b[f] + hs[n][f]*dinv[n];
// also materializes dinv[n] = rsqrt(deg[n]+1) for the scatter.
// block: 256 threads -> 128 rows x 32 cols; thread: 4 rows x 4 cols
#define KC 64
#define LDP 68
__global__ __launch_bounds__(256) void k_gemm(const float* __restrict__ x,
                                              const float* __restrict__ W,
                                              const float* __restrict__ b,
                                              const int* __restrict__ cnt,
                                              float* __restrict__ hs,
                                              float* __restrict__ dinv,
                                              float* __restrict__ out, int N) {
    __shared__ __align__(16) float sx[128 * LDP];
    __shared__ __align__(16) float sWt[F_OUT * LDP];
    const int tid = threadIdx.x;
    const int fbase = tid & 7;
    const int rbase = tid >> 3;
    const int row0 = blockIdx.x * 128;

    float acc[4][4];
    #pragma unroll
    for (int j = 0; j < 4; ++j)
        #pragma unroll
        for (int m = 0; m < 4; ++m) acc[j][m] = 0.f;

    for (int c = 0; c < F_IN / KC; ++c) {
        #pragma unroll
        for (int i = 0; i < 8; ++i) {
            int flat4 = i * 256 + tid;
            int r = flat4 >> 4;
            int q = flat4 & 15;
            float4 v = make_float4(0.f, 0.f, 0.f, 0.f);
            if (row0 + r < N)
                v = ((const float4*)x)[(size_t)(row0 + r) * (F_IN / 4) + c * (KC / 4) + q];
            *(float4*)(sx + r * LDP + q * 4) = v;
        }
        #pragma unroll
        for (int i = 0; i < 8; ++i) {
            int flat = i * 256 + tid;
            int k = flat >> 5;
            int f = flat & 31;
            sWt[f * LDP + k] = W[(size_t)(c * KC + k) * F_OUT + f];
        }
        __syncthreads();

        #pragma unroll 4
        for (int k0 = 0; k0 < KC; k0 += 4) {
            float4 wv[4], xv[4];
            #pragma unroll
            for (int m = 0; m < 4; ++m)
                wv[m] = *(const float4*)(sWt + (fbase + 8 * m) * LDP + k0);
            #pragma unroll
            for (int j = 0; j < 4; ++j)
                xv[j] = *(const float4*)(sx + (rbase + 32 * j) * LDP + k0);
            #pragma unroll
            for (int j = 0; j < 4; ++j)
                #pragma unroll
                for (int m = 0; m < 4; ++m)
                    acc[j][m] += xv[j].x * wv[m].x + xv[j].y * wv[m].y +
                                 xv[j].z * wv[m].z + xv[j].w * wv[m].w;
        }
        __syncthreads();
    }

    #pragma unroll
    for (int j = 0; j < 4; ++j) {
        int row = row0 + rbase + 32 * j;
        if (row < N) {
            float di = rsqrtf((float)cnt[row] + 1.0f);
            if (fbase == 0) dinv[row] = di;
            #pragma unroll
            for (int m = 0; m < 4; ++m) {
                float h_scaled = acc[j][m] * di;
                hs[(size_t)row * F_OUT + fbase + 8 * m] = h_scaled;
                out[(size_t)row * F_OUT + fbase + 8 * m] =
                    b[fbase + 8 * m] + h_scaled * di;   // bias + self-loop term
            }
        }
    }
}

// ---------- edge scatter: out[dst][f] += hs[src][f] * dinv[dst] ----------
// thread per (edge, feature): wave64 = 2 edges x 32 f -> the 32 atomic lanes
// per edge hit one contiguous 128B row (2 cache lines) — best-case coalescing
// for the memory-side atomic unit.
__global__ __launch_bounds__(256) void k_scatter(const int* __restrict__ ei,
                                                 const float* __restrict__ hs,
                                                 const float* __restrict__ dinv,
                                                 float* __restrict__ out,
                                                 const int* __restrict__ flag,
                                                 int E, int N) {
    long long gid = (long long)blockIdx.x * 256 + threadIdx.x;
    int e = (int)(gid >> 5);
    int f = (int)(gid & 31);
    if (e < E) {
        int m64 = *flag;
        int s = load_idx(ei, e, m64);
        int d = load_idx(ei, E + e, m64);
        if ((unsigned)s < (unsigned)N && (unsigned)d < (unsigned)N) {
            float v = hs[(size_t)s * F_OUT + f] * dinv[d];
            atomicAdd(&out[(size_t)d * F_OUT + f], v);
        }
    }
}

extern "C" void kernel_launch(void* const* d_in, const int* in_sizes, int n_in,
                              void* d_out, int out_size, void* d_ws, size_t ws_size,
                              hipStream_t stream) {
    const float* x  = (const float*)d_in[0];
    const int*   ei = (const int*)d_in[1];
    const float* W  = (const float*)d_in[2];
    const float* b  = (const float*)d_in[3];
    float* out = (float*)d_out;

    const int N = in_sizes[0] / F_IN;   // 100000
    const int E = in_sizes[1] / 2;      // 1600000

    float* hs   = (float*)d_ws;                    // N*32 floats (12.8 MB)
    int*   cnt  = (int*)(hs + (size_t)N * F_OUT);  // N ints
    float* dinv = (float*)(cnt + N);               // N floats
    int*   flag = (int*)(dinv + N);                // 1 int

    k_init   <<<(N + 255) / 256, 256, 0, stream>>>(cnt, ei, flag, N);
    k_count  <<<(E / 4 + 255) / 256, 256, 0, stream>>>(ei, cnt, flag, E, N);
    k_gemm   <<<(N + 127) / 128, 256, 0, stream>>>(x, W, b, cnt, hs, dinv, out, N);
    long long st = (long long)E * F_OUT;
    k_scatter<<<(int)((st + 255) / 256), 256, 0, stream>>>(ei, hs, dinv, out, flag, E, N);
}

// Round 6
// 365.094 us; speedup vs baseline: 1.7463x; 1.2115x over previous
//
#include <hip/hip_runtime.h>

#define F_IN  256
#define F_OUT 32

// packed f16 atomic add (no return) — global_atomic_pk_add_f16 (gfx90a+/CDNA4).
// data: one VGPR holding 2 x f16. addr: VGPR pair.
__device__ __forceinline__ void pk_add_f16(void* p, unsigned int packed) {
    asm volatile("global_atomic_pk_add_f16 %0, %1, off" :: "v"(p), "v"(packed) : "memory");
}

__device__ __forceinline__ unsigned int pack_f16x2(float a, float b) {
    union { _Float16 h[2]; unsigned int u; } r;
    r.h[0] = (_Float16)a;
    r.h[1] = (_Float16)b;
    return r.u;
}

// ---------- zero cnt + nbr accumulator, detect edge-index dtype ----------
// int64 little-endian with values < 2^31 => every odd 32-bit word is zero.
__global__ void k_zero(int* __restrict__ cnt, uint4* __restrict__ nbr4,
                       const int* __restrict__ ei, int* __restrict__ flag,
                       int N, int n4) {
    int i = blockIdx.x * 256 + threadIdx.x;
    if (i < n4) nbr4[i] = make_uint4(0, 0, 0, 0);
    if (i < N) cnt[i] = 0;
    if (i == 0) {
        int o = 0;
        for (int k = 1; k < 64; k += 2) o |= ei[k];
        *flag = (o == 0) ? 1 : 0;
    }
}

__device__ __forceinline__ int load_idx(const int* __restrict__ ei, int i, int mode64) {
    return mode64 ? ei[2 * i] : ei[i];
}

// ---------- degree count: 4 edges/thread, vectorized dst reads ----------
__global__ __launch_bounds__(256) void k_count(const int* __restrict__ ei,
                                               int* __restrict__ cnt,
                                               const int* __restrict__ flag,
                                               int E, int N) {
    int m64 = *flag;
    int t = blockIdx.x * 256 + threadIdx.x;
    int e0 = t * 4;
    if (e0 >= E) return;
    int d[4];
    if (e0 + 3 < E) {
        if (m64) {
            const int4* base = (const int4*)(ei + 2 * (size_t)E);
            int4 a = base[2 * t];
            int4 c = base[2 * t + 1];
            d[0] = a.x; d[1] = a.z; d[2] = c.x; d[3] = c.z;
        } else {
            int4 a = *(const int4*)(ei + (size_t)E + e0);
            d[0] = a.x; d[1] = a.y; d[2] = a.z; d[3] = a.w;
        }
        #pragma unroll
        for (int j = 0; j < 4; ++j)
            if ((unsigned)d[j] < (unsigned)N) atomicAdd(&cnt[d[j]], 1);
    } else {
        for (int e = e0; e < E; ++e) {
            int dd = load_idx(ei, E + e, m64);
            if ((unsigned)dd < (unsigned)N) atomicAdd(&cnt[dd], 1);
        }
    }
}

// ---------- register-tiled GEMM: hs[n][f] = (x@W)[n][f] * rsqrt(deg[n]+1) ----------
// block: 256 threads -> 128 rows x 32 cols; thread: 4 rows x 4 cols
#define KC 64
#define LDP 68
__global__ __launch_bounds__(256) void k_gemm(const float* __restrict__ x,
                                              const float* __restrict__ W,
                                              const int* __restrict__ cnt,
                                              float* __restrict__ hs, int N) {
    __shared__ __align__(16) float sx[128 * LDP];
    __shared__ __align__(16) float sWt[F_OUT * LDP];
    const int tid = threadIdx.x;
    const int fbase = tid & 7;
    const int rbase = tid >> 3;
    const int row0 = blockIdx.x * 128;

    float acc[4][4];
    #pragma unroll
    for (int j = 0; j < 4; ++j)
        #pragma unroll
        for (int m = 0; m < 4; ++m) acc[j][m] = 0.f;

    for (int c = 0; c < F_IN / KC; ++c) {
        #pragma unroll
        for (int i = 0; i < 8; ++i) {
            int flat4 = i * 256 + tid;
            int r = flat4 >> 4;
            int q = flat4 & 15;
            float4 v = make_float4(0.f, 0.f, 0.f, 0.f);
            if (row0 + r < N)
                v = ((const float4*)x)[(size_t)(row0 + r) * (F_IN / 4) + c * (KC / 4) + q];
            *(float4*)(sx + r * LDP + q * 4) = v;
        }
        #pragma unroll
        for (int i = 0; i < 8; ++i) {
            int flat = i * 256 + tid;
            int k = flat >> 5;
            int f = flat & 31;
            sWt[f * LDP + k] = W[(size_t)(c * KC + k) * F_OUT + f];
        }
        __syncthreads();

        #pragma unroll 4
        for (int k0 = 0; k0 < KC; k0 += 4) {
            float4 wv[4], xv[4];
            #pragma unroll
            for (int m = 0; m < 4; ++m)
                wv[m] = *(const float4*)(sWt + (fbase + 8 * m) * LDP + k0);
            #pragma unroll
            for (int j = 0; j < 4; ++j)
                xv[j] = *(const float4*)(sx + (rbase + 32 * j) * LDP + k0);
            #pragma unroll
            for (int j = 0; j < 4; ++j)
                #pragma unroll
                for (int m = 0; m < 4; ++m)
                    acc[j][m] += xv[j].x * wv[m].x + xv[j].y * wv[m].y +
                                 xv[j].z * wv[m].z + xv[j].w * wv[m].w;
        }
        __syncthreads();
    }

    #pragma unroll
    for (int j = 0; j < 4; ++j) {
        int row = row0 + rbase + 32 * j;
        if (row < N) {
            float di = rsqrtf((float)cnt[row] + 1.0f);
            #pragma unroll
            for (int m = 0; m < 4; ++m)
                hs[(size_t)row * F_OUT + fbase + 8 * m] = acc[j][m] * di;
        }
    }
}

// ---------- edge scatter: nbr[dst][f-pair] += f16x2(hs[src][f-pair]) ----------
// 1 thread per (edge, feature-pair): float2 gather + ONE pk_add_f16 (2 floats / op).
// 16 lanes per edge hit one contiguous 64B row.
__global__ __launch_bounds__(256) void k_scatter(const int* __restrict__ ei,
                                                 const float* __restrict__ hs,
                                                 unsigned int* __restrict__ nbr,
                                                 const int* __restrict__ flag,
                                                 int E, int N) {
    long long gid = (long long)blockIdx.x * 256 + threadIdx.x;
    int e = (int)(gid >> 4);
    int q = (int)(gid & 15);   // feature pair 0..15
    if (e < E) {
        int m64 = *flag;
        int s = load_idx(ei, e, m64);
        int d = load_idx(ei, E + e, m64);
        if ((unsigned)s < (unsigned)N && (unsigned)d < (unsigned)N) {
            float2 v = ((const float2*)(hs + (size_t)s * F_OUT))[q];
            pk_add_f16(&nbr[(size_t)d * (F_OUT / 2) + q], pack_f16x2(v.x, v.y));
        }
    }
}

// ---------- merge: out[n][f] = b[f] + dinv[n] * (hs[n][f] + nbr[n][f]) ----------
__global__ __launch_bounds__(256) void k_merge(const unsigned int* __restrict__ nbr,
                                               const float* __restrict__ hs,
                                               const int* __restrict__ cnt,
                                               const float* __restrict__ b,
                                               float* __restrict__ out, int N) {
    long long gid = (long long)blockIdx.x * 256 + threadIdx.x;
    int n = (int)(gid >> 4);
    int q = (int)(gid & 15);
    if (n >= N) return;
    float di = rsqrtf((float)cnt[n] + 1.0f);
    union { unsigned int u; _Float16 h[2]; } r;
    r.u = nbr[(size_t)n * (F_OUT / 2) + q];
    float2 hv = ((const float2*)(hs + (size_t)n * F_OUT))[q];
    float2 o;
    o.x = b[2 * q]     + di * (hv.x + (float)r.h[0]);
    o.y = b[2 * q + 1] + di * (hv.y + (float)r.h[1]);
    ((float2*)(out + (size_t)n * F_OUT))[q] = o;
}

extern "C" void kernel_launch(void* const* d_in, const int* in_sizes, int n_in,
                              void* d_out, int out_size, void* d_ws, size_t ws_size,
                              hipStream_t stream) {
    const float* x  = (const float*)d_in[0];
    const int*   ei = (const int*)d_in[1];
    const float* W  = (const float*)d_in[2];
    const float* b  = (const float*)d_in[3];
    float* out = (float*)d_out;

    const int N = in_sizes[0] / F_IN;   // 100000
    const int E = in_sizes[1] / 2;      // 1600000

    // ws layout: hs (N*32 f32) | nbr (N*16 u32 = N*32 f16) | cnt (N) | flag (1)
    float*        hs   = (float*)d_ws;
    unsigned int* nbr  = (unsigned int*)(hs + (size_t)N * F_OUT);
    int*          cnt  = (int*)(nbr + (size_t)N * (F_OUT / 2));
    int*          flag = cnt + N;

    const int n4 = N * 4;  // nbr as uint4 count
    k_zero   <<<(n4 + 255) / 256, 256, 0, stream>>>(cnt, (uint4*)nbr, ei, flag, N, n4);
    k_count  <<<(E / 4 + 255) / 256, 256, 0, stream>>>(ei, cnt, flag, E, N);
    k_gemm   <<<(N + 127) / 128, 256, 0, stream>>>(x, W, cnt, hs, N);
    long long st = (long long)E * (F_OUT / 2);
    k_scatter<<<(int)((st + 255) / 256), 256, 0, stream>>>(ei, hs, nbr, flag, E, N);
    long long mt = (long long)N * (F_OUT / 2);
    k_merge  <<<(int)((mt + 255) / 256), 256, 0, stream>>>(nbr, hs, cnt, b, out, N);
}